// Round 3
// baseline (433.411 us; speedup 1.0000x reference)
//
#include <hip/hip_runtime.h>

// Round 15: fuse gather->conv. gather12+conv12 -> conv12g, gather3+conv3_lin
// -> conv3g. Per-wave 32-row LDS tile (pitch 136, bank-safe); half-waves
// gather 16 rows each (8-deep unroll for latency), wave then MFMAs from its
// own tile -- no barriers (intra-wave LDS is in-order). W fragments read
// straight from global wbuf (L2-resident, 224KB) -- no W staging phases.
// Kills agg1/agg2/agg3 intermediates (~35MB HBM round trip) + 2 launches.
// conv1 output un-aliased from xm_bf (fusion would race in-place); rank
// arrays alias movie_out instead. hist_lds/prep2/basescan2/scan2/fill
// unchanged from R14.

typedef unsigned short u16;
typedef unsigned int u32;
typedef __attribute__((ext_vector_type(8))) short bf16x8;
typedef __attribute__((ext_vector_type(4))) float f32x4;

#define NMC 50000
#define NDC 20000
#define EC  600000
#define CM  64          // movie histogram copies
#define CD  32          // dem histogram copies
#define CHM (EC / CM)   // 9375
#define CHD (EC / CD)   // 18750
#define NWM (NMC / 2)   // 25000 packed words
#define NWD (NDC / 2)   // 10000

__device__ __forceinline__ float bf2f(u16 h) {
    union { u32 u; float f; } v; v.u = ((u32)h) << 16; return v.f;
}
__device__ __forceinline__ u16 f2bf(float f) {
    union { float f; u32 u; } v; v.f = f;
    u32 lsb = (v.u >> 16) & 1u;
    v.u += 0x7fffu + lsb;           // RNE
    return (u16)(v.u >> 16);
}

// ---------------- LDS histogram + rank (no global atomics) ----------------
__global__ __launch_bounds__(256)
void hist_lds(const int* __restrict__ dst_m, const int* __restrict__ dst_b,
              int* __restrict__ rank_m, int* __restrict__ rank_b,
              u32* __restrict__ histm, u32* __restrict__ histd)
{
    __shared__ u32 h[NWM];          // 100 KB; dem blocks use first NWD words
    const int b = blockIdx.x;
    const bool isM = b < CM;
    const int nw = isM ? NWM : NWD;
    for (int i = threadIdx.x; i < nw; i += 256) h[i] = 0;
    __syncthreads();
    if (isM) {
        const int e0 = b * CHM;
        const int e1 = min(EC, e0 + CHM);
        for (int e = e0 + threadIdx.x; e < e1; e += 256) {
            int d = dst_m[e];
            int sh = (d & 1) * 16;
            u32 old = atomicAdd(&h[d >> 1], 1u << sh);
            rank_m[e] = (old >> sh) & 0xffffu;
        }
        __syncthreads();
        for (int i = threadIdx.x; i < nw; i += 256)
            histm[(size_t)b * NWM + i] = h[i];
    } else {
        const int bb = b - CM;
        const int e0 = bb * CHD;
        const int e1 = min(EC, e0 + CHD);
        for (int e = e0 + threadIdx.x; e < e1; e += 256) {
            int d = dst_b[e];
            int sh = (d & 1) * 16;
            u32 old = atomicAdd(&h[d >> 1], 1u << sh);
            rank_b[e] = (old >> sh) & 0xffffu;
        }
        __syncthreads();
        for (int i = threadIdx.x; i < nw; i += 256)
            histd[(size_t)bb * NWD + i] = h[i];
    }
}

// ---------------- prep2: xm->bf16 | xd->bf16 | wfrag ----------------
__global__ __launch_bounds__(256)
void prep2(const float* __restrict__ xm, u16* __restrict__ xm_bf, int n8m,
           const float* __restrict__ xd, u16* __restrict__ xd_bf, int n8d,
           const float* __restrict__ w0, const float* __restrict__ w1,
           const float* __restrict__ w2, const float* __restrict__ w3,
           const float* __restrict__ w4, const float* __restrict__ w5,
           const float* __restrict__ w6, u16* __restrict__ wbuf,
           int TB, int TB2)
{
    const int b = blockIdx.x;
    if (b < TB + TB2) {
        const bool isM = b < TB;
        const float* src = isM ? xm : xd;
        u16* dst = isM ? xm_bf : xd_bf;
        int n8 = isM ? n8m : n8d;
        int i = (b - (isM ? 0 : TB)) * 256 + threadIdx.x;
        if (i >= n8) return;
        float4 a = ((const float4*)src)[2 * i];
        float4 c2 = ((const float4*)src)[2 * i + 1];
        ushort4 h0; h0.x = f2bf(a.x); h0.y = f2bf(a.y); h0.z = f2bf(a.z); h0.w = f2bf(a.w);
        ushort4 h1; h1.x = f2bf(c2.x); h1.y = f2bf(c2.y); h1.z = f2bf(c2.z); h1.w = f2bf(c2.w);
        ((ushort4*)dst)[2 * i]     = h0;
        ((ushort4*)dst)[2 * i + 1] = h1;
    } else {
        int bb = b - TB - TB2;
        const int widx = bb >> 6;
        const int o    = ((bb & 63) << 8) + threadIdx.x;
        const int OC   = (widx == 6) ? 64 : 128;
        if (o >= OC * 128) return;
        const float* W;
        switch (widx) {
            case 0: W = w0; break; case 1: W = w1; break; case 2: W = w2; break;
            case 3: W = w3; break; case 4: W = w4; break; case 5: W = w5; break;
            default: W = w6;
        }
        int j = o & 7;
        int lane = (o >> 3) & 63;
        int n, c;
        if (OC == 128) { n = (o >> 9) & 7; c = o >> 12; }
        else           { n = (o >> 9) & 3; c = o >> 11; }
        int col = n * 16 + (lane & 15);
        int k   = c * 32 + (lane >> 4) * 8 + j;
        wbuf[widx * 16384 + o] = f2bf(W[k * OC + col]);
    }
}

// ---------------- per-node scan over histogram copies (packed u16) ---------
__global__ __launch_bounds__(256)
void basescan2(u32* __restrict__ histm, u32* __restrict__ histd,
               int* __restrict__ deg_m, int* __restrict__ deg_b)
{
    int w = blockIdx.x * 256 + threadIdx.x;
    u32* hist; int* deg; int NW, C;
    if (w < NWM)            { hist = histm; deg = deg_m; NW = NWM; C = CM; }
    else if (w < NWM + NWD) { hist = histd; deg = deg_b; NW = NWD; C = CD; w -= NWM; }
    else return;
    u32 runlo = 0, runhi = 0;
    for (int c = 0; c < C; ++c) {
        u32 v = hist[(size_t)c * NW + w];
        hist[(size_t)c * NW + w] = runlo | (runhi << 16);
        runlo += v & 0xffffu;
        runhi += v >> 16;
    }
    deg[2 * w]     = (int)runlo;
    deg[2 * w + 1] = (int)runhi;
}

__device__ __forceinline__ int wave_incl_scan(int v, int lane) {
#pragma unroll
    for (int off = 1; off < 64; off <<= 1) {
        int t = __shfl_up(v, off, 64);
        if (lane >= off) v += t;
    }
    return v;
}

// exclusive scan + sentinel, 4 elems/thread
__global__ __launch_bounds__(1024)
void scan2_kernel(const int* __restrict__ degA, int* __restrict__ rpA, int nA,
                  const int* __restrict__ degB, int* __restrict__ rpB, int nB)
{
    const int* deg = blockIdx.x ? degB : degA;
    int* rp = blockIdx.x ? rpB : rpA;
    int n = blockIdx.x ? nB : nA;

    __shared__ int wsum[16];
    __shared__ int carry;
    const int tid = threadIdx.x, lane = tid & 63, wid = tid >> 6;
    if (tid == 0) carry = 0;
    __syncthreads();

    for (int base = 0; base < n; base += 4096) {
        int idx = base + tid * 4;
        int4 v = make_int4(0, 0, 0, 0);
        if (idx + 3 < n) v = *(const int4*)(deg + idx);
        else {
            if (idx + 0 < n) v.x = deg[idx + 0];
            if (idx + 1 < n) v.y = deg[idx + 1];
            if (idx + 2 < n) v.z = deg[idx + 2];
            if (idx + 3 < n) v.w = deg[idx + 3];
        }
        int s = v.x + v.y + v.z + v.w;
        int incl = wave_incl_scan(s, lane);
        if (lane == 63) wsum[wid] = incl;
        __syncthreads();
        if (wid == 0) {
            int t = (lane < 16) ? wsum[lane] : 0;
            int ti = wave_incl_scan(t, lane);
            if (lane < 16) wsum[lane] = ti - t;
        }
        __syncthreads();
        int base_t = carry + wsum[wid] + incl - s;
        if (idx + 3 < n) {
            int4 st;
            st.x = base_t;
            st.y = base_t + v.x;
            st.z = base_t + v.x + v.y;
            st.w = base_t + v.x + v.y + v.z;
            *(int4*)(rp + idx) = st;
        } else {
            if (idx + 0 < n) rp[idx + 0] = base_t;
            if (idx + 1 < n) rp[idx + 1] = base_t + v.x;
            if (idx + 2 < n) rp[idx + 2] = base_t + v.x + v.y;
            if (idx + 3 < n) rp[idx + 3] = base_t + v.x + v.y + v.z;
        }
        __syncthreads();
        if (tid == 1023) carry += wsum[15] + incl;
        __syncthreads();
    }
    if (tid == 0) rp[n] = carry;
}

// ---------------- atomic-free fill ----------------
__global__ __launch_bounds__(256)
void fill_kernel(const int* __restrict__ src_m, const int* __restrict__ dst_m,
                 const int* __restrict__ src_b, const int* __restrict__ dst_b,
                 const float* __restrict__ edge_w,
                 const int* __restrict__ rp_m, const int* __restrict__ rp_b,
                 const int* __restrict__ rank_m, const int* __restrict__ rank_b,
                 const u32* __restrict__ histm, const u32* __restrict__ histd,
                 int* __restrict__ srcs_m, int2* __restrict__ edges_b, int E)
{
    int t = blockIdx.x * 256 + threadIdx.x;
    if (t < E) {
        int d = dst_m[t];
        int c = t / CHM;
        u32 pk = histm[(size_t)c * NWM + (d >> 1)];
        int base = (pk >> ((d & 1) * 16)) & 0xffffu;
        int pos = rp_m[d] + base + rank_m[t];
        srcs_m[pos] = src_m[t];
    } else if (t < 2 * E) {
        int e = t - E;
        int d = dst_b[e];
        int c = e / CHD;
        u32 pkb = histd[(size_t)c * NWD + (d >> 1)];
        int base = (pkb >> ((d & 1) * 16)) & 0xffffu;
        int pos = rp_b[d] + base + rank_b[e];
        float x = edge_w[e];
        int2 pk;
        pk.x = src_b[e];
        pk.y = __float_as_int(1.0f / (1.0f + __expf(-x)));
        edges_b[pos] = pk;
    }
}

// ---------------- fused gather + conv1/conv2 ----------------
// Block = 128 rows (32/wave). Half-wave gathers 16 rows into the wave's LDS
// tile (pitch 136 u16); wave MFMAs from its own tile -- no barriers.
__global__ __launch_bounds__(256)
void conv12g(const u16* __restrict__ gtab,
             const int* __restrict__ srcs_m, const int2* __restrict__ edges_b,
             const int* __restrict__ rp_m, const int* __restrict__ rp_b,
             const u16* __restrict__ w1r, const u16* __restrict__ w1o,
             const float* __restrict__ b1, u16* __restrict__ C1, int N1, int cb1,
             const u16* __restrict__ xd_bf,
             const u16* __restrict__ w2r, const u16* __restrict__ w2o,
             const float* __restrict__ b2, u16* __restrict__ C2, int N2)
{
    __shared__ u16 tile[4][32][136];   // 34816 B

    const bool seg1 = (int)blockIdx.x < cb1;
    const int  base = seg1 ? blockIdx.x : (blockIdx.x - cb1);
    const int  N    = seg1 ? N1 : N2;
    const int* rp   = seg1 ? rp_m : rp_b;
    const u16* Aroot = seg1 ? gtab : xd_bf;
    const u16* Wr   = seg1 ? w1r : w2r;
    const u16* Wo   = seg1 ? w1o : w2o;
    const float* bias = seg1 ? b1 : b2;
    u16* C = seg1 ? C1 : C2;

    const int tid = threadIdx.x;
    const int wv  = tid >> 6;
    const int hw  = (tid >> 5) & 1;
    const int cl  = tid & 31;
    const int m0  = (base * 4 + wv) * 32;

    // ---- gather phase: 16 nodes per half-wave, 8-deep unroll ----
    for (int j = 0; j < 16; ++j) {
        const int k = hw * 16 + j;
        int node = m0 + k; if (node >= N) node = N - 1;
        int i = rp[node], end = rp[node + 1];
        float4 acc = make_float4(0.f, 0.f, 0.f, 0.f);
        if (seg1) {
            for (; i + 8 <= end; i += 8) {
                int s0 = srcs_m[i+0], s1 = srcs_m[i+1], s2 = srcs_m[i+2], s3 = srcs_m[i+3];
                int s4 = srcs_m[i+4], s5 = srcs_m[i+5], s6 = srcs_m[i+6], s7 = srcs_m[i+7];
                ushort4 v0 = *(const ushort4*)(gtab + (size_t)s0 * 128 + cl * 4);
                ushort4 v1 = *(const ushort4*)(gtab + (size_t)s1 * 128 + cl * 4);
                ushort4 v2 = *(const ushort4*)(gtab + (size_t)s2 * 128 + cl * 4);
                ushort4 v3 = *(const ushort4*)(gtab + (size_t)s3 * 128 + cl * 4);
                ushort4 v4 = *(const ushort4*)(gtab + (size_t)s4 * 128 + cl * 4);
                ushort4 v5 = *(const ushort4*)(gtab + (size_t)s5 * 128 + cl * 4);
                ushort4 v6 = *(const ushort4*)(gtab + (size_t)s6 * 128 + cl * 4);
                ushort4 v7 = *(const ushort4*)(gtab + (size_t)s7 * 128 + cl * 4);
                acc.x += ((bf2f(v0.x)+bf2f(v1.x)) + (bf2f(v2.x)+bf2f(v3.x)))
                       + ((bf2f(v4.x)+bf2f(v5.x)) + (bf2f(v6.x)+bf2f(v7.x)));
                acc.y += ((bf2f(v0.y)+bf2f(v1.y)) + (bf2f(v2.y)+bf2f(v3.y)))
                       + ((bf2f(v4.y)+bf2f(v5.y)) + (bf2f(v6.y)+bf2f(v7.y)));
                acc.z += ((bf2f(v0.z)+bf2f(v1.z)) + (bf2f(v2.z)+bf2f(v3.z)))
                       + ((bf2f(v4.z)+bf2f(v5.z)) + (bf2f(v6.z)+bf2f(v7.z)));
                acc.w += ((bf2f(v0.w)+bf2f(v1.w)) + (bf2f(v2.w)+bf2f(v3.w)))
                       + ((bf2f(v4.w)+bf2f(v5.w)) + (bf2f(v6.w)+bf2f(v7.w)));
            }
            for (; i < end; ++i) {
                int s = srcs_m[i];
                ushort4 v = *(const ushort4*)(gtab + (size_t)s * 128 + cl * 4);
                acc.x += bf2f(v.x); acc.y += bf2f(v.y);
                acc.z += bf2f(v.z); acc.w += bf2f(v.w);
            }
        } else {
            for (; i + 8 <= end; i += 8) {
                int2 p0 = edges_b[i+0], p1 = edges_b[i+1], p2 = edges_b[i+2], p3 = edges_b[i+3];
                int2 p4 = edges_b[i+4], p5 = edges_b[i+5], p6 = edges_b[i+6], p7 = edges_b[i+7];
                ushort4 v0 = *(const ushort4*)(gtab + (size_t)p0.x * 128 + cl * 4);
                ushort4 v1 = *(const ushort4*)(gtab + (size_t)p1.x * 128 + cl * 4);
                ushort4 v2 = *(const ushort4*)(gtab + (size_t)p2.x * 128 + cl * 4);
                ushort4 v3 = *(const ushort4*)(gtab + (size_t)p3.x * 128 + cl * 4);
                ushort4 v4 = *(const ushort4*)(gtab + (size_t)p4.x * 128 + cl * 4);
                ushort4 v5 = *(const ushort4*)(gtab + (size_t)p5.x * 128 + cl * 4);
                ushort4 v6 = *(const ushort4*)(gtab + (size_t)p6.x * 128 + cl * 4);
                ushort4 v7 = *(const ushort4*)(gtab + (size_t)p7.x * 128 + cl * 4);
                float w0 = __int_as_float(p0.y), w1 = __int_as_float(p1.y);
                float w2 = __int_as_float(p2.y), w3 = __int_as_float(p3.y);
                float w4 = __int_as_float(p4.y), w5 = __int_as_float(p5.y);
                float w6 = __int_as_float(p6.y), w7 = __int_as_float(p7.y);
                acc.x = fmaf(w0, bf2f(v0.x), acc.x); acc.y = fmaf(w0, bf2f(v0.y), acc.y);
                acc.z = fmaf(w0, bf2f(v0.z), acc.z); acc.w = fmaf(w0, bf2f(v0.w), acc.w);
                acc.x = fmaf(w1, bf2f(v1.x), acc.x); acc.y = fmaf(w1, bf2f(v1.y), acc.y);
                acc.z = fmaf(w1, bf2f(v1.z), acc.z); acc.w = fmaf(w1, bf2f(v1.w), acc.w);
                acc.x = fmaf(w2, bf2f(v2.x), acc.x); acc.y = fmaf(w2, bf2f(v2.y), acc.y);
                acc.z = fmaf(w2, bf2f(v2.z), acc.z); acc.w = fmaf(w2, bf2f(v2.w), acc.w);
                acc.x = fmaf(w3, bf2f(v3.x), acc.x); acc.y = fmaf(w3, bf2f(v3.y), acc.y);
                acc.z = fmaf(w3, bf2f(v3.z), acc.z); acc.w = fmaf(w3, bf2f(v3.w), acc.w);
                acc.x = fmaf(w4, bf2f(v4.x), acc.x); acc.y = fmaf(w4, bf2f(v4.y), acc.y);
                acc.z = fmaf(w4, bf2f(v4.z), acc.z); acc.w = fmaf(w4, bf2f(v4.w), acc.w);
                acc.x = fmaf(w5, bf2f(v5.x), acc.x); acc.y = fmaf(w5, bf2f(v5.y), acc.y);
                acc.z = fmaf(w5, bf2f(v5.z), acc.z); acc.w = fmaf(w5, bf2f(v5.w), acc.w);
                acc.x = fmaf(w6, bf2f(v6.x), acc.x); acc.y = fmaf(w6, bf2f(v6.y), acc.y);
                acc.z = fmaf(w6, bf2f(v6.z), acc.z); acc.w = fmaf(w6, bf2f(v6.w), acc.w);
                acc.x = fmaf(w7, bf2f(v7.x), acc.x); acc.y = fmaf(w7, bf2f(v7.y), acc.y);
                acc.z = fmaf(w7, bf2f(v7.z), acc.z); acc.w = fmaf(w7, bf2f(v7.w), acc.w);
            }
            for (; i < end; ++i) {
                int2 pk = edges_b[i];
                float w = __int_as_float(pk.y);
                ushort4 v = *(const ushort4*)(gtab + (size_t)pk.x * 128 + cl * 4);
                acc.x = fmaf(w, bf2f(v.x), acc.x); acc.y = fmaf(w, bf2f(v.y), acc.y);
                acc.z = fmaf(w, bf2f(v.z), acc.z); acc.w = fmaf(w, bf2f(v.w), acc.w);
            }
        }
        ushort4 st;
        st.x = f2bf(acc.x); st.y = f2bf(acc.y);
        st.z = f2bf(acc.z); st.w = f2bf(acc.w);
        *(ushort4*)(&tile[wv][k][cl * 4]) = st;
    }

    // ---- conv phase (wave-local; LDS in-order within wave, no barrier) ----
    const int lane = tid & 63;
    const int lr   = lane & 15;
    const int quad = lane >> 4;
    int r0 = m0 + lr;      if (r0 >= N) r0 = N - 1;
    int r1 = m0 + 16 + lr; if (r1 >= N) r1 = N - 1;

    f32x4 acc[2][8];
#pragma unroll
    for (int mt = 0; mt < 2; ++mt)
#pragma unroll
        for (int n = 0; n < 8; ++n) acc[mt][n] = (f32x4){0.f, 0.f, 0.f, 0.f};

#pragma unroll
    for (int c = 0; c < 4; ++c) {
        const int kb = c * 32 + quad * 8;
        bf16x8 a0 = *(const bf16x8*)(&tile[wv][lr][kb]);
        bf16x8 a1 = *(const bf16x8*)(&tile[wv][16 + lr][kb]);
        const u16* wp = Wr + c * 4096 + lane * 8;
#pragma unroll
        for (int n = 0; n < 8; ++n) {
            bf16x8 b = *(const bf16x8*)(wp + n * 512);
            acc[0][n] = __builtin_amdgcn_mfma_f32_16x16x32_bf16(a0, b, acc[0][n], 0, 0, 0);
            acc[1][n] = __builtin_amdgcn_mfma_f32_16x16x32_bf16(a1, b, acc[1][n], 0, 0, 0);
        }
    }
#pragma unroll
    for (int c = 0; c < 4; ++c) {
        const int kb = c * 32 + quad * 8;
        bf16x8 a0 = *(const bf16x8*)(Aroot + (size_t)r0 * 128 + kb);
        bf16x8 a1 = *(const bf16x8*)(Aroot + (size_t)r1 * 128 + kb);
        const u16* wp = Wo + c * 4096 + lane * 8;
#pragma unroll
        for (int n = 0; n < 8; ++n) {
            bf16x8 b = *(const bf16x8*)(wp + n * 512);
            acc[0][n] = __builtin_amdgcn_mfma_f32_16x16x32_bf16(a0, b, acc[0][n], 0, 0, 0);
            acc[1][n] = __builtin_amdgcn_mfma_f32_16x16x32_bf16(a1, b, acc[1][n], 0, 0, 0);
        }
    }

#pragma unroll
    for (int mt = 0; mt < 2; ++mt) {
#pragma unroll
        for (int n = 0; n < 8; ++n) {
            const int col = n * 16 + lr;
            const float b = bias[col];
#pragma unroll
            for (int r = 0; r < 4; ++r) {
                int row = m0 + mt * 16 + quad * 4 + r;
                if (row >= N) continue;
                C[(size_t)row * 128 + col] = f2bf(fmaxf(acc[mt][n][r] + b, 0.f));
            }
        }
    }
}

// ---------------- fused gather3 + conv3 + lin ----------------
__global__ __launch_bounds__(256)
void conv3g(const u16* __restrict__ movie, const int2* __restrict__ edges_b,
            const int* __restrict__ rp_b,
            const u16* __restrict__ w3r, const u16* __restrict__ w3o,
            const float* __restrict__ bias3, const u16* __restrict__ t2,
            const u16* __restrict__ wl, const float* __restrict__ bias_l,
            float* __restrict__ out, int N)
{
    __shared__ u16 tile[4][32][136];

    const int tid = threadIdx.x;
    const int wv  = tid >> 6;
    const int hw  = (tid >> 5) & 1;
    const int cl  = tid & 31;
    const int m0  = (blockIdx.x * 4 + wv) * 32;

    // ---- gather phase (weighted, from movie) ----
    for (int j = 0; j < 16; ++j) {
        const int k = hw * 16 + j;
        int node = m0 + k; if (node >= N) node = N - 1;
        int i = rp_b[node], end = rp_b[node + 1];
        float4 acc = make_float4(0.f, 0.f, 0.f, 0.f);
        for (; i + 8 <= end; i += 8) {
            int2 p0 = edges_b[i+0], p1 = edges_b[i+1], p2 = edges_b[i+2], p3 = edges_b[i+3];
            int2 p4 = edges_b[i+4], p5 = edges_b[i+5], p6 = edges_b[i+6], p7 = edges_b[i+7];
            ushort4 v0 = *(const ushort4*)(movie + (size_t)p0.x * 128 + cl * 4);
            ushort4 v1 = *(const ushort4*)(movie + (size_t)p1.x * 128 + cl * 4);
            ushort4 v2 = *(const ushort4*)(movie + (size_t)p2.x * 128 + cl * 4);
            ushort4 v3 = *(const ushort4*)(movie + (size_t)p3.x * 128 + cl * 4);
            ushort4 v4 = *(const ushort4*)(movie + (size_t)p4.x * 128 + cl * 4);
            ushort4 v5 = *(const ushort4*)(movie + (size_t)p5.x * 128 + cl * 4);
            ushort4 v6 = *(const ushort4*)(movie + (size_t)p6.x * 128 + cl * 4);
            ushort4 v7 = *(const ushort4*)(movie + (size_t)p7.x * 128 + cl * 4);
            float w0 = __int_as_float(p0.y), w1 = __int_as_float(p1.y);
            float w2 = __int_as_float(p2.y), w3 = __int_as_float(p3.y);
            float w4 = __int_as_float(p4.y), w5 = __int_as_float(p5.y);
            float w6 = __int_as_float(p6.y), w7 = __int_as_float(p7.y);
            acc.x = fmaf(w0, bf2f(v0.x), acc.x); acc.y = fmaf(w0, bf2f(v0.y), acc.y);
            acc.z = fmaf(w0, bf2f(v0.z), acc.z); acc.w = fmaf(w0, bf2f(v0.w), acc.w);
            acc.x = fmaf(w1, bf2f(v1.x), acc.x); acc.y = fmaf(w1, bf2f(v1.y), acc.y);
            acc.z = fmaf(w1, bf2f(v1.z), acc.z); acc.w = fmaf(w1, bf2f(v1.w), acc.w);
            acc.x = fmaf(w2, bf2f(v2.x), acc.x); acc.y = fmaf(w2, bf2f(v2.y), acc.y);
            acc.z = fmaf(w2, bf2f(v2.z), acc.z); acc.w = fmaf(w2, bf2f(v2.w), acc.w);
            acc.x = fmaf(w3, bf2f(v3.x), acc.x); acc.y = fmaf(w3, bf2f(v3.y), acc.y);
            acc.z = fmaf(w3, bf2f(v3.z), acc.z); acc.w = fmaf(w3, bf2f(v3.w), acc.w);
            acc.x = fmaf(w4, bf2f(v4.x), acc.x); acc.y = fmaf(w4, bf2f(v4.y), acc.y);
            acc.z = fmaf(w4, bf2f(v4.z), acc.z); acc.w = fmaf(w4, bf2f(v4.w), acc.w);
            acc.x = fmaf(w5, bf2f(v5.x), acc.x); acc.y = fmaf(w5, bf2f(v5.y), acc.y);
            acc.z = fmaf(w5, bf2f(v5.z), acc.z); acc.w = fmaf(w5, bf2f(v5.w), acc.w);
            acc.x = fmaf(w6, bf2f(v6.x), acc.x); acc.y = fmaf(w6, bf2f(v6.y), acc.y);
            acc.z = fmaf(w6, bf2f(v6.z), acc.z); acc.w = fmaf(w6, bf2f(v6.w), acc.w);
            acc.x = fmaf(w7, bf2f(v7.x), acc.x); acc.y = fmaf(w7, bf2f(v7.y), acc.y);
            acc.z = fmaf(w7, bf2f(v7.z), acc.z); acc.w = fmaf(w7, bf2f(v7.w), acc.w);
        }
        for (; i < end; ++i) {
            int2 pk = edges_b[i];
            float w = __int_as_float(pk.y);
            ushort4 v = *(const ushort4*)(movie + (size_t)pk.x * 128 + cl * 4);
            acc.x = fmaf(w, bf2f(v.x), acc.x); acc.y = fmaf(w, bf2f(v.y), acc.y);
            acc.z = fmaf(w, bf2f(v.z), acc.z); acc.w = fmaf(w, bf2f(v.w), acc.w);
        }
        ushort4 st;
        st.x = f2bf(acc.x); st.y = f2bf(acc.y);
        st.z = f2bf(acc.z); st.w = f2bf(acc.w);
        *(ushort4*)(&tile[wv][k][cl * 4]) = st;
    }

    // ---- conv3 phase ----
    const int lane = tid & 63;
    const int lr   = lane & 15;
    const int quad = lane >> 4;
    int r0 = m0 + lr;      if (r0 >= N) r0 = N - 1;
    int r1 = m0 + 16 + lr; if (r1 >= N) r1 = N - 1;

    f32x4 acc[2][8];
#pragma unroll
    for (int mt = 0; mt < 2; ++mt)
#pragma unroll
        for (int n = 0; n < 8; ++n) acc[mt][n] = (f32x4){0.f, 0.f, 0.f, 0.f};

#pragma unroll
    for (int c = 0; c < 4; ++c) {
        const int kb = c * 32 + quad * 8;
        bf16x8 a0 = *(const bf16x8*)(&tile[wv][lr][kb]);
        bf16x8 a1 = *(const bf16x8*)(&tile[wv][16 + lr][kb]);
        const u16* wp = w3r + c * 4096 + lane * 8;
#pragma unroll
        for (int n = 0; n < 8; ++n) {
            bf16x8 b = *(const bf16x8*)(wp + n * 512);
            acc[0][n] = __builtin_amdgcn_mfma_f32_16x16x32_bf16(a0, b, acc[0][n], 0, 0, 0);
            acc[1][n] = __builtin_amdgcn_mfma_f32_16x16x32_bf16(a1, b, acc[1][n], 0, 0, 0);
        }
    }
#pragma unroll
    for (int c = 0; c < 4; ++c) {
        const int kb = c * 32 + quad * 8;
        bf16x8 a0 = *(const bf16x8*)(t2 + (size_t)r0 * 128 + kb);
        bf16x8 a1 = *(const bf16x8*)(t2 + (size_t)r1 * 128 + kb);
        const u16* wp = w3o + c * 4096 + lane * 8;
#pragma unroll
        for (int n = 0; n < 8; ++n) {
            bf16x8 b = *(const bf16x8*)(wp + n * 512);
            acc[0][n] = __builtin_amdgcn_mfma_f32_16x16x32_bf16(a0, b, acc[0][n], 0, 0, 0);
            acc[1][n] = __builtin_amdgcn_mfma_f32_16x16x32_bf16(a1, b, acc[1][n], 0, 0, 0);
        }
    }

    // relu'd bf16 conv3 output back into the wave's tile (agg dead now)
#pragma unroll
    for (int mt = 0; mt < 2; ++mt) {
#pragma unroll
        for (int n = 0; n < 8; ++n) {
            const int col = n * 16 + lr;
            const float b = bias3[col];
#pragma unroll
            for (int r = 0; r < 4; ++r) {
                int row = mt * 16 + quad * 4 + r;
                tile[wv][row][col] = f2bf(fmaxf(acc[mt][n][r] + b, 0.f));
            }
        }
    }

    // ---- lin phase ----
    f32x4 acc2[2][4];
#pragma unroll
    for (int mt = 0; mt < 2; ++mt)
#pragma unroll
        for (int n = 0; n < 4; ++n) acc2[mt][n] = (f32x4){0.f, 0.f, 0.f, 0.f};

#pragma unroll
    for (int c = 0; c < 4; ++c) {
        const int kb = c * 32 + quad * 8;
        bf16x8 a0 = *(const bf16x8*)(&tile[wv][lr][kb]);
        bf16x8 a1 = *(const bf16x8*)(&tile[wv][16 + lr][kb]);
#pragma unroll
        for (int n = 0; n < 4; ++n) {
            bf16x8 b = *(const bf16x8*)(wl + c * 2048 + n * 512 + lane * 8);
            acc2[0][n] = __builtin_amdgcn_mfma_f32_16x16x32_bf16(a0, b, acc2[0][n], 0, 0, 0);
            acc2[1][n] = __builtin_amdgcn_mfma_f32_16x16x32_bf16(a1, b, acc2[1][n], 0, 0, 0);
        }
    }

#pragma unroll
    for (int mt = 0; mt < 2; ++mt) {
#pragma unroll
        for (int n = 0; n < 4; ++n) {
            const int col = n * 16 + lr;
            const float b = bias_l[col];
#pragma unroll
            for (int r = 0; r < 4; ++r) {
                int row = m0 + mt * 16 + quad * 4 + r;
                if (row >= N) continue;
                out[(size_t)row * 64 + col] = acc2[mt][n][r] + b;
            }
        }
    }
}

extern "C" void kernel_launch(void* const* d_in, const int* in_sizes, int n_in,
                              void* d_out, int out_size, void* d_ws, size_t ws_size,
                              hipStream_t stream)
{
    const float* x_meas  = (const float*)d_in[0];
    const float* x_dem   = (const float*)d_in[1];
    const int*   src_m   = (const int*)d_in[2];
    const int*   dst_m   = (const int*)d_in[3];
    const int*   src_b   = (const int*)d_in[4];
    const int*   dst_b   = (const int*)d_in[5];
    const float* edge_w  = (const float*)d_in[6];
    const float* W_rel1  = (const float*)d_in[7];
    const float* b_rel1  = (const float*)d_in[8];
    const float* W_root1 = (const float*)d_in[9];
    const float* W_rel2  = (const float*)d_in[10];
    const float* b_rel2  = (const float*)d_in[11];
    const float* W_root2 = (const float*)d_in[12];
    const float* W_rel3  = (const float*)d_in[13];
    const float* b_rel3  = (const float*)d_in[14];
    const float* W_root3 = (const float*)d_in[15];
    const float* W_lin   = (const float*)d_in[16];
    const float* b_lin   = (const float*)d_in[17];
    float* out = (float*)d_out;

    const int NM = NMC, ND = NDC, E = EC;

    char* p = (char*)d_ws;
    auto alloc = [&](size_t bytes) { char* r = p; p += (bytes + 511) & ~(size_t)511; return r; };
    u32*   histm   = (u32*)alloc((size_t)CM * NWM * 4);   // 6.4 MB
    u32*   histd   = (u32*)alloc((size_t)CD * NWD * 4);   // 1.28 MB
    int*   deg_m   = (int*)alloc((size_t)NM * 4);
    int*   deg_b   = (int*)alloc((size_t)ND * 4);
    int*   rp_m    = (int*)alloc((size_t)(NM + 1) * 4);
    int*   rp_b    = (int*)alloc((size_t)(ND + 1) * 4);
    int*   srcs_m  = (int*)alloc((size_t)E * 4);
    int2*  edges_b = (int2*)alloc((size_t)E * 8);
    u16*   xm_bf   = (u16*)alloc((size_t)NM * 128 * 2);   // 12.8 MB (pristine table)
    u16*   movie   = (u16*)alloc((size_t)NM * 128 * 2);   // 12.8 MB conv1 out
    u16*   xd_bf   = (u16*)alloc((size_t)ND * 128 * 2);   // 5.12 MB
    u16*   t2      = (u16*)alloc((size_t)ND * 128 * 2);   // 5.12 MB conv2 out
    u16*   wbuf    = (u16*)alloc(7 * 16384 * 2);          // 224 KB
    // aliases (stream-serial lifetimes):
    int* rank_m = (int*)movie;         // rank dies at fill; movie written by conv12g (after)
    int* rank_b = rank_m + E;          // 4.8 MB total <= 12.8 MB

    const int TB  = (NM * 16 + 255) / 256;     // 3125
    const int TB2 = (ND * 16 + 255) / 256;     // 1250
    const int WB  = 448;
    const int HB  = (2 * E + 255) / 256;       // 4688 (fill grid)

    hist_lds<<<CM + CD, 256, 0, stream>>>(dst_m, dst_b, rank_m, rank_b, histm, histd);

    prep2<<<TB + TB2 + WB, 256, 0, stream>>>(
        x_meas, xm_bf, NM * 16, x_dem, xd_bf, ND * 16,
        W_rel1, W_root1, W_rel2, W_root2, W_rel3, W_root3, W_lin, wbuf,
        TB, TB2);

    basescan2<<<(NWM + NWD + 255) / 256, 256, 0, stream>>>(histm, histd, deg_m, deg_b);
    scan2_kernel<<<2, 1024, 0, stream>>>(deg_m, rp_m, NM, deg_b, rp_b, ND);
    fill_kernel<<<HB, 256, 0, stream>>>(src_m, dst_m, src_b, dst_b, edge_w,
                                        rp_m, rp_b, rank_m, rank_b,
                                        histm, histd, srcs_m, edges_b, E);

    const int cb1 = (NM + 127) / 128;   // 391
    const int cb2 = (ND + 127) / 128;   // 157
    u16* w1r = wbuf + 0 * 16384; u16* w1o = wbuf + 1 * 16384;
    u16* w2r = wbuf + 2 * 16384; u16* w2o = wbuf + 3 * 16384;
    u16* w3r = wbuf + 4 * 16384; u16* w3o = wbuf + 5 * 16384;
    u16* wl  = wbuf + 6 * 16384;

    conv12g<<<cb1 + cb2, 256, 0, stream>>>(xm_bf, srcs_m, edges_b, rp_m, rp_b,
                                           w1r, w1o, b_rel1, movie, NM, cb1,
                                           xd_bf, w2r, w2o, b_rel2, t2, ND);

    conv3g<<<cb2, 256, 0, stream>>>(movie, edges_b, rp_b, w3r, w3o, b_rel3,
                                    t2, wl, b_lin, out, ND);
}

// Round 4
// 325.341 us; speedup vs baseline: 1.3322x; 1.3322x over previous
//
#include <hip/hip_runtime.h>

// Round 16: fusion at the RIGHT granularity. R15 failed because 128-row
// blocks collapsed the grid (548/157 blocks, 17% occupancy) and serialized
// 16 nodes/half-wave. This round: 32-row blocks, R14's proven gather loop
// (1 node per 32-lane group per step, 4 steps), grid 2188/625 blocks ->
// same wave pressure as R14's gather12. One barrier, then 4 waves split
// the 128 output cols (acc[2][2] each), B-frags from L2-resident wbuf,
// root term streamed from global. LDS tile 8.7KB (pitch 136 = 2-way bank
// aliasing, free). Kills agg round-trips + 2 launches.
// hist_lds/prep2/basescan2/scan2/fill unchanged from R14.

typedef unsigned short u16;
typedef unsigned int u32;
typedef __attribute__((ext_vector_type(8))) short bf16x8;
typedef __attribute__((ext_vector_type(4))) float f32x4;

#define NMC 50000
#define NDC 20000
#define EC  600000
#define CM  64          // movie histogram copies
#define CD  32          // dem histogram copies
#define CHM (EC / CM)   // 9375
#define CHD (EC / CD)   // 18750
#define NWM (NMC / 2)   // 25000 packed words
#define NWD (NDC / 2)   // 10000

__device__ __forceinline__ float bf2f(u16 h) {
    union { u32 u; float f; } v; v.u = ((u32)h) << 16; return v.f;
}
__device__ __forceinline__ u16 f2bf(float f) {
    union { float f; u32 u; } v; v.f = f;
    u32 lsb = (v.u >> 16) & 1u;
    v.u += 0x7fffu + lsb;           // RNE
    return (u16)(v.u >> 16);
}

// ---------------- LDS histogram + rank (no global atomics) ----------------
__global__ __launch_bounds__(256)
void hist_lds(const int* __restrict__ dst_m, const int* __restrict__ dst_b,
              int* __restrict__ rank_m, int* __restrict__ rank_b,
              u32* __restrict__ histm, u32* __restrict__ histd)
{
    __shared__ u32 h[NWM];          // 100 KB; dem blocks use first NWD words
    const int b = blockIdx.x;
    const bool isM = b < CM;
    const int nw = isM ? NWM : NWD;
    for (int i = threadIdx.x; i < nw; i += 256) h[i] = 0;
    __syncthreads();
    if (isM) {
        const int e0 = b * CHM;
        const int e1 = min(EC, e0 + CHM);
        for (int e = e0 + threadIdx.x; e < e1; e += 256) {
            int d = dst_m[e];
            int sh = (d & 1) * 16;
            u32 old = atomicAdd(&h[d >> 1], 1u << sh);
            rank_m[e] = (old >> sh) & 0xffffu;
        }
        __syncthreads();
        for (int i = threadIdx.x; i < nw; i += 256)
            histm[(size_t)b * NWM + i] = h[i];
    } else {
        const int bb = b - CM;
        const int e0 = bb * CHD;
        const int e1 = min(EC, e0 + CHD);
        for (int e = e0 + threadIdx.x; e < e1; e += 256) {
            int d = dst_b[e];
            int sh = (d & 1) * 16;
            u32 old = atomicAdd(&h[d >> 1], 1u << sh);
            rank_b[e] = (old >> sh) & 0xffffu;
        }
        __syncthreads();
        for (int i = threadIdx.x; i < nw; i += 256)
            histd[(size_t)bb * NWD + i] = h[i];
    }
}

// ---------------- prep2: xm->bf16 | xd->bf16 | wfrag ----------------
__global__ __launch_bounds__(256)
void prep2(const float* __restrict__ xm, u16* __restrict__ xm_bf, int n8m,
           const float* __restrict__ xd, u16* __restrict__ xd_bf, int n8d,
           const float* __restrict__ w0, const float* __restrict__ w1,
           const float* __restrict__ w2, const float* __restrict__ w3,
           const float* __restrict__ w4, const float* __restrict__ w5,
           const float* __restrict__ w6, u16* __restrict__ wbuf,
           int TB, int TB2)
{
    const int b = blockIdx.x;
    if (b < TB + TB2) {
        const bool isM = b < TB;
        const float* src = isM ? xm : xd;
        u16* dst = isM ? xm_bf : xd_bf;
        int n8 = isM ? n8m : n8d;
        int i = (b - (isM ? 0 : TB)) * 256 + threadIdx.x;
        if (i >= n8) return;
        float4 a = ((const float4*)src)[2 * i];
        float4 c2 = ((const float4*)src)[2 * i + 1];
        ushort4 h0; h0.x = f2bf(a.x); h0.y = f2bf(a.y); h0.z = f2bf(a.z); h0.w = f2bf(a.w);
        ushort4 h1; h1.x = f2bf(c2.x); h1.y = f2bf(c2.y); h1.z = f2bf(c2.z); h1.w = f2bf(c2.w);
        ((ushort4*)dst)[2 * i]     = h0;
        ((ushort4*)dst)[2 * i + 1] = h1;
    } else {
        int bb = b - TB - TB2;
        const int widx = bb >> 6;
        const int o    = ((bb & 63) << 8) + threadIdx.x;
        const int OC   = (widx == 6) ? 64 : 128;
        if (o >= OC * 128) return;
        const float* W;
        switch (widx) {
            case 0: W = w0; break; case 1: W = w1; break; case 2: W = w2; break;
            case 3: W = w3; break; case 4: W = w4; break; case 5: W = w5; break;
            default: W = w6;
        }
        int j = o & 7;
        int lane = (o >> 3) & 63;
        int n, c;
        if (OC == 128) { n = (o >> 9) & 7; c = o >> 12; }
        else           { n = (o >> 9) & 3; c = o >> 11; }
        int col = n * 16 + (lane & 15);
        int k   = c * 32 + (lane >> 4) * 8 + j;
        wbuf[widx * 16384 + o] = f2bf(W[k * OC + col]);
    }
}

// ---------------- per-node scan over histogram copies (packed u16) ---------
__global__ __launch_bounds__(256)
void basescan2(u32* __restrict__ histm, u32* __restrict__ histd,
               int* __restrict__ deg_m, int* __restrict__ deg_b)
{
    int w = blockIdx.x * 256 + threadIdx.x;
    u32* hist; int* deg; int NW, C;
    if (w < NWM)            { hist = histm; deg = deg_m; NW = NWM; C = CM; }
    else if (w < NWM + NWD) { hist = histd; deg = deg_b; NW = NWD; C = CD; w -= NWM; }
    else return;
    u32 runlo = 0, runhi = 0;
    for (int c = 0; c < C; ++c) {
        u32 v = hist[(size_t)c * NW + w];
        hist[(size_t)c * NW + w] = runlo | (runhi << 16);
        runlo += v & 0xffffu;
        runhi += v >> 16;
    }
    deg[2 * w]     = (int)runlo;
    deg[2 * w + 1] = (int)runhi;
}

__device__ __forceinline__ int wave_incl_scan(int v, int lane) {
#pragma unroll
    for (int off = 1; off < 64; off <<= 1) {
        int t = __shfl_up(v, off, 64);
        if (lane >= off) v += t;
    }
    return v;
}

// exclusive scan + sentinel, 4 elems/thread
__global__ __launch_bounds__(1024)
void scan2_kernel(const int* __restrict__ degA, int* __restrict__ rpA, int nA,
                  const int* __restrict__ degB, int* __restrict__ rpB, int nB)
{
    const int* deg = blockIdx.x ? degB : degA;
    int* rp = blockIdx.x ? rpB : rpA;
    int n = blockIdx.x ? nB : nA;

    __shared__ int wsum[16];
    __shared__ int carry;
    const int tid = threadIdx.x, lane = tid & 63, wid = tid >> 6;
    if (tid == 0) carry = 0;
    __syncthreads();

    for (int base = 0; base < n; base += 4096) {
        int idx = base + tid * 4;
        int4 v = make_int4(0, 0, 0, 0);
        if (idx + 3 < n) v = *(const int4*)(deg + idx);
        else {
            if (idx + 0 < n) v.x = deg[idx + 0];
            if (idx + 1 < n) v.y = deg[idx + 1];
            if (idx + 2 < n) v.z = deg[idx + 2];
            if (idx + 3 < n) v.w = deg[idx + 3];
        }
        int s = v.x + v.y + v.z + v.w;
        int incl = wave_incl_scan(s, lane);
        if (lane == 63) wsum[wid] = incl;
        __syncthreads();
        if (wid == 0) {
            int t = (lane < 16) ? wsum[lane] : 0;
            int ti = wave_incl_scan(t, lane);
            if (lane < 16) wsum[lane] = ti - t;
        }
        __syncthreads();
        int base_t = carry + wsum[wid] + incl - s;
        if (idx + 3 < n) {
            int4 st;
            st.x = base_t;
            st.y = base_t + v.x;
            st.z = base_t + v.x + v.y;
            st.w = base_t + v.x + v.y + v.z;
            *(int4*)(rp + idx) = st;
        } else {
            if (idx + 0 < n) rp[idx + 0] = base_t;
            if (idx + 1 < n) rp[idx + 1] = base_t + v.x;
            if (idx + 2 < n) rp[idx + 2] = base_t + v.x + v.y;
            if (idx + 3 < n) rp[idx + 3] = base_t + v.x + v.y + v.z;
        }
        __syncthreads();
        if (tid == 1023) carry += wsum[15] + incl;
        __syncthreads();
    }
    if (tid == 0) rp[n] = carry;
}

// ---------------- atomic-free fill ----------------
__global__ __launch_bounds__(256)
void fill_kernel(const int* __restrict__ src_m, const int* __restrict__ dst_m,
                 const int* __restrict__ src_b, const int* __restrict__ dst_b,
                 const float* __restrict__ edge_w,
                 const int* __restrict__ rp_m, const int* __restrict__ rp_b,
                 const int* __restrict__ rank_m, const int* __restrict__ rank_b,
                 const u32* __restrict__ histm, const u32* __restrict__ histd,
                 int* __restrict__ srcs_m, int2* __restrict__ edges_b, int E)
{
    int t = blockIdx.x * 256 + threadIdx.x;
    if (t < E) {
        int d = dst_m[t];
        int c = t / CHM;
        u32 pk = histm[(size_t)c * NWM + (d >> 1)];
        int base = (pk >> ((d & 1) * 16)) & 0xffffu;
        int pos = rp_m[d] + base + rank_m[t];
        srcs_m[pos] = src_m[t];
    } else if (t < 2 * E) {
        int e = t - E;
        int d = dst_b[e];
        int c = e / CHD;
        u32 pkb = histd[(size_t)c * NWD + (d >> 1)];
        int base = (pkb >> ((d & 1) * 16)) & 0xffffu;
        int pos = rp_b[d] + base + rank_b[e];
        float x = edge_w[e];
        int2 pk;
        pk.x = src_b[e];
        pk.y = __float_as_int(1.0f / (1.0f + __expf(-x)));
        edges_b[pos] = pk;
    }
}

// ---------------- fused gather + conv1/conv2, 32 rows/block ----------------
// 8 groups of 32 lanes gather 4 nodes each (R14 inner loop); barrier; 4
// waves each compute 32 rows x 32 cols (acc[2][2]), B from global wbuf.
__global__ __launch_bounds__(256)
void conv12g(const u16* __restrict__ gtab,
             const int* __restrict__ srcs_m, const int2* __restrict__ edges_b,
             const int* __restrict__ rp_m, const int* __restrict__ rp_b,
             const u16* __restrict__ w1r, const u16* __restrict__ w1o,
             const float* __restrict__ b1, u16* __restrict__ C1, int N1, int cbm,
             const u16* __restrict__ xd_bf,
             const u16* __restrict__ w2r, const u16* __restrict__ w2o,
             const float* __restrict__ b2, u16* __restrict__ C2, int N2)
{
    __shared__ u16 tile[32][136];   // 8704 B

    const bool seg1 = (int)blockIdx.x < cbm;
    const int  base = seg1 ? blockIdx.x : (blockIdx.x - cbm);
    const int  N    = seg1 ? N1 : N2;
    const int* rp   = seg1 ? rp_m : rp_b;
    const u16* Aroot = seg1 ? gtab : xd_bf;
    const u16* Wr   = seg1 ? w1r : w2r;
    const u16* Wo   = seg1 ? w1o : w2o;
    const float* bias = seg1 ? b1 : b2;
    u16* C = seg1 ? C1 : C2;

    const int tid = threadIdx.x;
    const int g   = tid >> 5;       // 8 gather groups
    const int cl  = tid & 31;
    const int m0  = base * 32;

    // ---- gather phase: 4 nodes per group (R14 loop body) ----
    for (int j = 0; j < 4; ++j) {
        const int k = g * 4 + j;
        int node = m0 + k; if (node >= N) node = N - 1;
        int i = rp[node], end = rp[node + 1];
        float4 acc = make_float4(0.f, 0.f, 0.f, 0.f);
        if (seg1) {
            for (; i + 4 <= end; i += 4) {
                int s0 = srcs_m[i], s1 = srcs_m[i + 1], s2 = srcs_m[i + 2], s3 = srcs_m[i + 3];
                ushort4 v0 = *(const ushort4*)(gtab + (size_t)s0 * 128 + cl * 4);
                ushort4 v1 = *(const ushort4*)(gtab + (size_t)s1 * 128 + cl * 4);
                ushort4 v2 = *(const ushort4*)(gtab + (size_t)s2 * 128 + cl * 4);
                ushort4 v3 = *(const ushort4*)(gtab + (size_t)s3 * 128 + cl * 4);
                acc.x += (bf2f(v0.x) + bf2f(v1.x)) + (bf2f(v2.x) + bf2f(v3.x));
                acc.y += (bf2f(v0.y) + bf2f(v1.y)) + (bf2f(v2.y) + bf2f(v3.y));
                acc.z += (bf2f(v0.z) + bf2f(v1.z)) + (bf2f(v2.z) + bf2f(v3.z));
                acc.w += (bf2f(v0.w) + bf2f(v1.w)) + (bf2f(v2.w) + bf2f(v3.w));
            }
            for (; i < end; ++i) {
                int s = srcs_m[i];
                ushort4 v = *(const ushort4*)(gtab + (size_t)s * 128 + cl * 4);
                acc.x += bf2f(v.x); acc.y += bf2f(v.y);
                acc.z += bf2f(v.z); acc.w += bf2f(v.w);
            }
        } else {
            for (; i + 4 <= end; i += 4) {
                int2 p0 = edges_b[i],     p1 = edges_b[i + 1];
                int2 p2 = edges_b[i + 2], p3 = edges_b[i + 3];
                float w0 = __int_as_float(p0.y), w1 = __int_as_float(p1.y);
                float w2 = __int_as_float(p2.y), w3 = __int_as_float(p3.y);
                ushort4 v0 = *(const ushort4*)(gtab + (size_t)p0.x * 128 + cl * 4);
                ushort4 v1 = *(const ushort4*)(gtab + (size_t)p1.x * 128 + cl * 4);
                ushort4 v2 = *(const ushort4*)(gtab + (size_t)p2.x * 128 + cl * 4);
                ushort4 v3 = *(const ushort4*)(gtab + (size_t)p3.x * 128 + cl * 4);
                acc.x = fmaf(w0, bf2f(v0.x), acc.x); acc.y = fmaf(w0, bf2f(v0.y), acc.y);
                acc.z = fmaf(w0, bf2f(v0.z), acc.z); acc.w = fmaf(w0, bf2f(v0.w), acc.w);
                acc.x = fmaf(w1, bf2f(v1.x), acc.x); acc.y = fmaf(w1, bf2f(v1.y), acc.y);
                acc.z = fmaf(w1, bf2f(v1.z), acc.z); acc.w = fmaf(w1, bf2f(v1.w), acc.w);
                acc.x = fmaf(w2, bf2f(v2.x), acc.x); acc.y = fmaf(w2, bf2f(v2.y), acc.y);
                acc.z = fmaf(w2, bf2f(v2.z), acc.z); acc.w = fmaf(w2, bf2f(v2.w), acc.w);
                acc.x = fmaf(w3, bf2f(v3.x), acc.x); acc.y = fmaf(w3, bf2f(v3.y), acc.y);
                acc.z = fmaf(w3, bf2f(v3.z), acc.z); acc.w = fmaf(w3, bf2f(v3.w), acc.w);
            }
            for (; i < end; ++i) {
                int2 pk = edges_b[i];
                float w = __int_as_float(pk.y);
                ushort4 v = *(const ushort4*)(gtab + (size_t)pk.x * 128 + cl * 4);
                acc.x = fmaf(w, bf2f(v.x), acc.x); acc.y = fmaf(w, bf2f(v.y), acc.y);
                acc.z = fmaf(w, bf2f(v.z), acc.z); acc.w = fmaf(w, bf2f(v.w), acc.w);
            }
        }
        ushort4 st;
        st.x = f2bf(acc.x); st.y = f2bf(acc.y);
        st.z = f2bf(acc.z); st.w = f2bf(acc.w);
        *(ushort4*)(&tile[k][cl * 4]) = st;
    }
    __syncthreads();

    // ---- conv phase: wave wv computes 32 rows x cols [wv*32, wv*32+32) ----
    const int lane = tid & 63;
    const int wv   = tid >> 6;
    const int lr   = lane & 15;
    const int quad = lane >> 4;
    int r0 = m0 + lr;      if (r0 >= N) r0 = N - 1;
    int r1 = m0 + 16 + lr; if (r1 >= N) r1 = N - 1;

    f32x4 acc[2][2];
#pragma unroll
    for (int mt = 0; mt < 2; ++mt)
#pragma unroll
        for (int nn = 0; nn < 2; ++nn) acc[mt][nn] = (f32x4){0.f, 0.f, 0.f, 0.f};

#pragma unroll
    for (int c = 0; c < 4; ++c) {
        const int kb = c * 32 + quad * 8;
        bf16x8 a0 = *(const bf16x8*)(&tile[lr][kb]);
        bf16x8 a1 = *(const bf16x8*)(&tile[16 + lr][kb]);
#pragma unroll
        for (int nn = 0; nn < 2; ++nn) {
            const int n = wv * 2 + nn;
            bf16x8 b = *(const bf16x8*)(Wr + c * 4096 + n * 512 + lane * 8);
            acc[0][nn] = __builtin_amdgcn_mfma_f32_16x16x32_bf16(a0, b, acc[0][nn], 0, 0, 0);
            acc[1][nn] = __builtin_amdgcn_mfma_f32_16x16x32_bf16(a1, b, acc[1][nn], 0, 0, 0);
        }
    }
#pragma unroll
    for (int c = 0; c < 4; ++c) {
        const int kb = c * 32 + quad * 8;
        bf16x8 a0 = *(const bf16x8*)(Aroot + (size_t)r0 * 128 + kb);
        bf16x8 a1 = *(const bf16x8*)(Aroot + (size_t)r1 * 128 + kb);
#pragma unroll
        for (int nn = 0; nn < 2; ++nn) {
            const int n = wv * 2 + nn;
            bf16x8 b = *(const bf16x8*)(Wo + c * 4096 + n * 512 + lane * 8);
            acc[0][nn] = __builtin_amdgcn_mfma_f32_16x16x32_bf16(a0, b, acc[0][nn], 0, 0, 0);
            acc[1][nn] = __builtin_amdgcn_mfma_f32_16x16x32_bf16(a1, b, acc[1][nn], 0, 0, 0);
        }
    }

#pragma unroll
    for (int mt = 0; mt < 2; ++mt) {
#pragma unroll
        for (int nn = 0; nn < 2; ++nn) {
            const int col = (wv * 2 + nn) * 16 + lr;
            const float b = bias[col];
#pragma unroll
            for (int r = 0; r < 4; ++r) {
                int row = m0 + mt * 16 + quad * 4 + r;
                if (row >= N) continue;
                C[(size_t)row * 128 + col] = f2bf(fmaxf(acc[mt][nn][r] + b, 0.f));
            }
        }
    }
}

// ---------------- fused gather3 + conv3 + lin, 32 rows/block ----------------
__global__ __launch_bounds__(256)
void conv3g(const u16* __restrict__ movie, const int2* __restrict__ edges_b,
            const int* __restrict__ rp_b,
            const u16* __restrict__ w3r, const u16* __restrict__ w3o,
            const float* __restrict__ bias3, const u16* __restrict__ t2,
            const u16* __restrict__ wl, const float* __restrict__ bias_l,
            float* __restrict__ out, int N)
{
    __shared__ u16 tile[32][136];
    __shared__ u16 tile2[32][136];

    const int tid = threadIdx.x;
    const int g   = tid >> 5;
    const int cl  = tid & 31;
    const int m0  = blockIdx.x * 32;

    // ---- gather phase (weighted, from movie) ----
    for (int j = 0; j < 4; ++j) {
        const int k = g * 4 + j;
        int node = m0 + k; if (node >= N) node = N - 1;
        int i = rp_b[node], end = rp_b[node + 1];
        float4 acc = make_float4(0.f, 0.f, 0.f, 0.f);
        for (; i + 4 <= end; i += 4) {
            int2 p0 = edges_b[i],     p1 = edges_b[i + 1];
            int2 p2 = edges_b[i + 2], p3 = edges_b[i + 3];
            float w0 = __int_as_float(p0.y), w1 = __int_as_float(p1.y);
            float w2 = __int_as_float(p2.y), w3 = __int_as_float(p3.y);
            ushort4 v0 = *(const ushort4*)(movie + (size_t)p0.x * 128 + cl * 4);
            ushort4 v1 = *(const ushort4*)(movie + (size_t)p1.x * 128 + cl * 4);
            ushort4 v2 = *(const ushort4*)(movie + (size_t)p2.x * 128 + cl * 4);
            ushort4 v3 = *(const ushort4*)(movie + (size_t)p3.x * 128 + cl * 4);
            acc.x = fmaf(w0, bf2f(v0.x), acc.x); acc.y = fmaf(w0, bf2f(v0.y), acc.y);
            acc.z = fmaf(w0, bf2f(v0.z), acc.z); acc.w = fmaf(w0, bf2f(v0.w), acc.w);
            acc.x = fmaf(w1, bf2f(v1.x), acc.x); acc.y = fmaf(w1, bf2f(v1.y), acc.y);
            acc.z = fmaf(w1, bf2f(v1.z), acc.z); acc.w = fmaf(w1, bf2f(v1.w), acc.w);
            acc.x = fmaf(w2, bf2f(v2.x), acc.x); acc.y = fmaf(w2, bf2f(v2.y), acc.y);
            acc.z = fmaf(w2, bf2f(v2.z), acc.z); acc.w = fmaf(w2, bf2f(v2.w), acc.w);
            acc.x = fmaf(w3, bf2f(v3.x), acc.x); acc.y = fmaf(w3, bf2f(v3.y), acc.y);
            acc.z = fmaf(w3, bf2f(v3.z), acc.z); acc.w = fmaf(w3, bf2f(v3.w), acc.w);
        }
        for (; i < end; ++i) {
            int2 pk = edges_b[i];
            float w = __int_as_float(pk.y);
            ushort4 v = *(const ushort4*)(movie + (size_t)pk.x * 128 + cl * 4);
            acc.x = fmaf(w, bf2f(v.x), acc.x); acc.y = fmaf(w, bf2f(v.y), acc.y);
            acc.z = fmaf(w, bf2f(v.z), acc.z); acc.w = fmaf(w, bf2f(v.w), acc.w);
        }
        ushort4 st;
        st.x = f2bf(acc.x); st.y = f2bf(acc.y);
        st.z = f2bf(acc.z); st.w = f2bf(acc.w);
        *(ushort4*)(&tile[k][cl * 4]) = st;
    }
    __syncthreads();

    // ---- conv3 phase: wave wv -> cols [wv*32, wv*32+32) ----
    const int lane = tid & 63;
    const int wv   = tid >> 6;
    const int lr   = lane & 15;
    const int quad = lane >> 4;
    int r0 = m0 + lr;      if (r0 >= N) r0 = N - 1;
    int r1 = m0 + 16 + lr; if (r1 >= N) r1 = N - 1;

    f32x4 acc[2][2];
#pragma unroll
    for (int mt = 0; mt < 2; ++mt)
#pragma unroll
        for (int nn = 0; nn < 2; ++nn) acc[mt][nn] = (f32x4){0.f, 0.f, 0.f, 0.f};

#pragma unroll
    for (int c = 0; c < 4; ++c) {
        const int kb = c * 32 + quad * 8;
        bf16x8 a0 = *(const bf16x8*)(&tile[lr][kb]);
        bf16x8 a1 = *(const bf16x8*)(&tile[16 + lr][kb]);
#pragma unroll
        for (int nn = 0; nn < 2; ++nn) {
            const int n = wv * 2 + nn;
            bf16x8 b = *(const bf16x8*)(w3r + c * 4096 + n * 512 + lane * 8);
            acc[0][nn] = __builtin_amdgcn_mfma_f32_16x16x32_bf16(a0, b, acc[0][nn], 0, 0, 0);
            acc[1][nn] = __builtin_amdgcn_mfma_f32_16x16x32_bf16(a1, b, acc[1][nn], 0, 0, 0);
        }
    }
#pragma unroll
    for (int c = 0; c < 4; ++c) {
        const int kb = c * 32 + quad * 8;
        bf16x8 a0 = *(const bf16x8*)(t2 + (size_t)r0 * 128 + kb);
        bf16x8 a1 = *(const bf16x8*)(t2 + (size_t)r1 * 128 + kb);
#pragma unroll
        for (int nn = 0; nn < 2; ++nn) {
            const int n = wv * 2 + nn;
            bf16x8 b = *(const bf16x8*)(w3o + c * 4096 + n * 512 + lane * 8);
            acc[0][nn] = __builtin_amdgcn_mfma_f32_16x16x32_bf16(a0, b, acc[0][nn], 0, 0, 0);
            acc[1][nn] = __builtin_amdgcn_mfma_f32_16x16x32_bf16(a1, b, acc[1][nn], 0, 0, 0);
        }
    }

    // relu'd conv3 tile (each wave writes its own 32-col slice)
#pragma unroll
    for (int mt = 0; mt < 2; ++mt) {
#pragma unroll
        for (int nn = 0; nn < 2; ++nn) {
            const int col = (wv * 2 + nn) * 16 + lr;
            const float b = bias3[col];
#pragma unroll
            for (int r = 0; r < 4; ++r) {
                int row = mt * 16 + quad * 4 + r;
                tile2[row][col] = f2bf(fmaxf(acc[mt][nn][r] + b, 0.f));
            }
        }
    }
    __syncthreads();

    // ---- lin phase: wave wv -> its 16-col slice (64 cols total) ----
    f32x4 acc2[2];
    acc2[0] = (f32x4){0.f, 0.f, 0.f, 0.f};
    acc2[1] = (f32x4){0.f, 0.f, 0.f, 0.f};

#pragma unroll
    for (int c = 0; c < 4; ++c) {
        const int kb = c * 32 + quad * 8;
        bf16x8 a0 = *(const bf16x8*)(&tile2[lr][kb]);
        bf16x8 a1 = *(const bf16x8*)(&tile2[16 + lr][kb]);
        bf16x8 b = *(const bf16x8*)(wl + c * 2048 + wv * 512 + lane * 8);
        acc2[0] = __builtin_amdgcn_mfma_f32_16x16x32_bf16(a0, b, acc2[0], 0, 0, 0);
        acc2[1] = __builtin_amdgcn_mfma_f32_16x16x32_bf16(a1, b, acc2[1], 0, 0, 0);
    }

    const float bl = bias_l[wv * 16 + lr];
#pragma unroll
    for (int mt = 0; mt < 2; ++mt) {
#pragma unroll
        for (int r = 0; r < 4; ++r) {
            int row = m0 + mt * 16 + quad * 4 + r;
            if (row >= N) continue;
            out[(size_t)row * 64 + wv * 16 + lr] = acc2[mt][r] + bl;
        }
    }
}

extern "C" void kernel_launch(void* const* d_in, const int* in_sizes, int n_in,
                              void* d_out, int out_size, void* d_ws, size_t ws_size,
                              hipStream_t stream)
{
    const float* x_meas  = (const float*)d_in[0];
    const float* x_dem   = (const float*)d_in[1];
    const int*   src_m   = (const int*)d_in[2];
    const int*   dst_m   = (const int*)d_in[3];
    const int*   src_b   = (const int*)d_in[4];
    const int*   dst_b   = (const int*)d_in[5];
    const float* edge_w  = (const float*)d_in[6];
    const float* W_rel1  = (const float*)d_in[7];
    const float* b_rel1  = (const float*)d_in[8];
    const float* W_root1 = (const float*)d_in[9];
    const float* W_rel2  = (const float*)d_in[10];
    const float* b_rel2  = (const float*)d_in[11];
    const float* W_root2 = (const float*)d_in[12];
    const float* W_rel3  = (const float*)d_in[13];
    const float* b_rel3  = (const float*)d_in[14];
    const float* W_root3 = (const float*)d_in[15];
    const float* W_lin   = (const float*)d_in[16];
    const float* b_lin   = (const float*)d_in[17];
    float* out = (float*)d_out;

    const int NM = NMC, ND = NDC, E = EC;

    char* p = (char*)d_ws;
    auto alloc = [&](size_t bytes) { char* r = p; p += (bytes + 511) & ~(size_t)511; return r; };
    u32*   histm   = (u32*)alloc((size_t)CM * NWM * 4);   // 6.4 MB
    u32*   histd   = (u32*)alloc((size_t)CD * NWD * 4);   // 1.28 MB
    int*   deg_m   = (int*)alloc((size_t)NM * 4);
    int*   deg_b   = (int*)alloc((size_t)ND * 4);
    int*   rp_m    = (int*)alloc((size_t)(NM + 1) * 4);
    int*   rp_b    = (int*)alloc((size_t)(ND + 1) * 4);
    int*   srcs_m  = (int*)alloc((size_t)E * 4);
    int2*  edges_b = (int2*)alloc((size_t)E * 8);
    u16*   xm_bf   = (u16*)alloc((size_t)NM * 128 * 2);   // 12.8 MB (pristine table)
    u16*   movie   = (u16*)alloc((size_t)NM * 128 * 2);   // 12.8 MB conv1 out
    u16*   xd_bf   = (u16*)alloc((size_t)ND * 128 * 2);   // 5.12 MB
    u16*   t2      = (u16*)alloc((size_t)ND * 128 * 2);   // 5.12 MB conv2 out
    u16*   wbuf    = (u16*)alloc(7 * 16384 * 2);          // 224 KB
    // aliases (stream-serial lifetimes):
    int* rank_m = (int*)movie;         // rank dies at fill; movie written by conv12g (after)
    int* rank_b = rank_m + E;          // 4.8 MB total <= 12.8 MB

    const int TB  = (NM * 16 + 255) / 256;     // 3125
    const int TB2 = (ND * 16 + 255) / 256;     // 1250
    const int WB  = 448;
    const int HB  = (2 * E + 255) / 256;       // 4688 (fill grid)

    hist_lds<<<CM + CD, 256, 0, stream>>>(dst_m, dst_b, rank_m, rank_b, histm, histd);

    prep2<<<TB + TB2 + WB, 256, 0, stream>>>(
        x_meas, xm_bf, NM * 16, x_dem, xd_bf, ND * 16,
        W_rel1, W_root1, W_rel2, W_root2, W_rel3, W_root3, W_lin, wbuf,
        TB, TB2);

    basescan2<<<(NWM + NWD + 255) / 256, 256, 0, stream>>>(histm, histd, deg_m, deg_b);
    scan2_kernel<<<2, 1024, 0, stream>>>(deg_m, rp_m, NM, deg_b, rp_b, ND);
    fill_kernel<<<HB, 256, 0, stream>>>(src_m, dst_m, src_b, dst_b, edge_w,
                                        rp_m, rp_b, rank_m, rank_b,
                                        histm, histd, srcs_m, edges_b, E);

    const int cbm = (NM + 31) / 32;   // 1563
    const int cbd = (ND + 31) / 32;   // 625
    u16* w1r = wbuf + 0 * 16384; u16* w1o = wbuf + 1 * 16384;
    u16* w2r = wbuf + 2 * 16384; u16* w2o = wbuf + 3 * 16384;
    u16* w3r = wbuf + 4 * 16384; u16* w3o = wbuf + 5 * 16384;
    u16* wl  = wbuf + 6 * 16384;

    conv12g<<<cbm + cbd, 256, 0, stream>>>(xm_bf, srcs_m, edges_b, rp_m, rp_b,
                                           w1r, w1o, b_rel1, movie, NM, cbm,
                                           xd_bf, w2r, w2o, b_rel2, t2, ND);

    conv3g<<<cbd, 256, 0, stream>>>(movie, edges_b, rp_b, w3r, w3o, b_rel3,
                                    t2, wl, b_lin, out, ND);
}